// Round 1
// baseline (112.752 us; speedup 1.0000x reference)
//
#include <hip/hip_runtime.h>
#include <math.h>

// Problem constants (from reference setup_inputs)
#define N_  2
#define C_  64
#define S_  4
#define H_  64
#define W_  44
#define HW_       (H_ * W_)          // 2816
#define CH_STRIDE (S_ * HW_)         // 11264 elements between channels
#define NSTRIDE   (C_ * S_ * HW_)    // 720896 elements between n-batches
#define NEG_BIG   (-1e30f)

// One wave per (b, y, x) pixel. Lane k < 49 owns window tap k (dy=k/7-3, dx=k%7-3).
// Channel dot product: lane i preloads f0[ch=i]; inner loop broadcasts via __shfl
// (readlane) and gathers f1 at the tap coordinate. Then wave-wide softmax over the
// 49 taps and expected-offset reduction.
__global__ __launch_bounds__(256) void flow_kernel(
    const float* __restrict__ f0,
    const float* __restrict__ f1,
    float* __restrict__ out)
{
    const int tid  = threadIdx.x;
    const int lane = tid & 63;
    const int wid  = tid >> 6;
    const int bid  = blockIdx.x;

    // 11 blocks per row (44 px / 4 waves), 64 rows, 8 batches
    const int x = (bid % 11) * 4 + wid;
    const int y = (bid / 11) % H_;
    const int b = bid / (11 * H_);
    const int n_idx = b >> 2;   // b = n_idx*S + s_idx
    const int s_idx = b & 3;

    const int base = n_idx * NSTRIDE + s_idx * HW_;

    // tap coords for this lane
    const int k  = (lane < 49) ? lane : 48;
    const int dx = k % 7 - 3;
    const int dy = k / 7 - 3;
    const int sx = x + dx;
    const int sy = y + dy;
    const bool valid = (lane < 49) & (sx >= 0) & (sx < W_) & (sy >= 0) & (sy < H_);
    // clamped address for invalid lanes (result masked later)
    const int sxc = min(max(sx, 0), W_ - 1);
    const int syc = min(max(sy, 0), H_ - 1);

    const float* p1 = f1 + base + syc * W_ + sxc;

    // lane i holds f0 value for channel i at this pixel
    const float f0r = f0[base + lane * CH_STRIDE + y * W_ + x];

    float acc = 0.0f;
    #pragma unroll
    for (int ch = 0; ch < C_; ++ch) {
        const float a = __shfl(f0r, ch, 64);       // wave-uniform broadcast (readlane)
        const float v = p1[ch * CH_STRIDE];        // 7x7-patch gather
        acc = fmaf(a, v, acc);
    }

    float corr = valid ? (acc * 0.125f) : NEG_BIG;  // 1/sqrt(64)

    // wave-wide max
    float m = corr;
    #pragma unroll
    for (int off = 32; off; off >>= 1)
        m = fmaxf(m, __shfl_xor(m, off, 64));

    float e  = __expf(corr - m);                    // invalid lanes -> 0
    float ex = e * (float)dx;
    float ey = e * (float)dy;

    #pragma unroll
    for (int off = 32; off; off >>= 1) {
        e  += __shfl_xor(e,  off, 64);
        ex += __shfl_xor(ex, off, 64);
        ey += __shfl_xor(ey, off, 64);
    }

    if (lane == 0) {
        const float inv = 1.0f / e;
        // out layout: (n, 2, s, h, w)
        const int ob = (n_idx * 2) * S_ * HW_ + s_idx * HW_ + y * W_ + x;
        out[ob]            = ex * inv;   // flow x
        out[ob + S_ * HW_] = ey * inv;   // flow y
    }
}

extern "C" void kernel_launch(void* const* d_in, const int* in_sizes, int n_in,
                              void* d_out, int out_size, void* d_ws, size_t ws_size,
                              hipStream_t stream) {
    const float* f0 = (const float*)d_in[0];
    const float* f1 = (const float*)d_in[1];
    float* out = (float*)d_out;

    const int blocks = (N_ * S_) * H_ * (W_ / 4);  // 8 * 64 * 11 = 5632
    flow_kernel<<<blocks, 256, 0, stream>>>(f0, f1, out);
}

// Round 2
// 96.109 us; speedup vs baseline: 1.1732x; 1.1732x over previous
//
#include <hip/hip_runtime.h>
#include <math.h>

// Problem constants (from reference setup_inputs)
#define N_  2
#define C_  64
#define S_  4
#define H_  64
#define W_  44
#define HW_       (H_ * W_)          // 2816
#define CH_STRIDE (S_ * HW_)         // 11264 elements between channels
#define NSTRIDE   (C_ * S_ * HW_)    // 720896 elements between n-batches

// One block per (b, y): 512 blocks x 512 threads (8 waves).
// Wave wid owns channels [wid*8, wid*8+8). Lane = x (0..43 active).
// Each lane accumulates acc[49] (7x7 taps) over its channel chunk with
// coalesced row loads; LDS tree-reduce across the 8 waves; wave 0 does the
// per-lane softmax + expected-flow entirely in registers.
__global__ __launch_bounds__(512) void flow_kernel(
    const float* __restrict__ f0,
    const float* __restrict__ f1,
    float* __restrict__ out)
{
    const int tid  = threadIdx.x;
    const int lane = tid & 63;
    const int wid  = tid >> 6;

    // b = blockIdx % 8 -> same-batch blocks land on the same XCD (L2 locality)
    const int b = blockIdx.x & 7;
    const int y = blockIdx.x >> 3;
    const int n_idx = b >> 2;
    const int s_idx = b & 3;

    const int base = n_idx * NSTRIDE + s_idx * HW_;
    const int x    = lane;
    const int xc   = min(x, W_ - 1);   // clamp so inactive lanes stay in-bounds

    __shared__ float red[4][W_][49];   // 34.5 KB

    float acc[49];
    #pragma unroll
    for (int k = 0; k < 49; ++k) acc[k] = 0.0f;

    // per-lane column clamp + zero-mask for each dx
    unsigned cmask[7];
    int      ccol[7];
    #pragma unroll
    for (int dx = 0; dx < 7; ++dx) {
        const int col = x + dx - 3;
        const bool ok = (col >= 0) && (col < W_);
        cmask[dx] = ok ? 0xffffffffu : 0u;
        ccol[dx]  = min(max(col, 0), W_ - 1);
    }

    const float* f0b = f0 + base + y * W_ + xc;
    const float* f1b = f1 + base;

    const int ch0 = wid * 8;
    #pragma unroll
    for (int ci = 0; ci < 8; ++ci) {
        const int ch = ch0 + ci;
        const float a = f0b[(size_t)ch * CH_STRIDE];
        const float* cb = f1b + (size_t)ch * CH_STRIDE;
        #pragma unroll
        for (int dy = 0; dy < 7; ++dy) {
            const int row = y + dy - 3;
            if (row < 0 || row >= H_) continue;   // wave-uniform skip
            const float* rp = cb + row * W_;
            #pragma unroll
            for (int dx = 0; dx < 7; ++dx) {
                float v = rp[ccol[dx]];                               // coalesced
                v = __uint_as_float(__float_as_uint(v) & cmask[dx]);  // zero-pad cols
                acc[dy * 7 + dx] = fmaf(a, v, acc[dy * 7 + dx]);
            }
        }
    }

    // LDS tree reduction across the 8 channel-chunk waves.
    // Layout [slot][x][k]: word-stride 49 per lane -> bank stride 17 (coprime 32).
    #pragma unroll
    for (int step = 4; step >= 1; step >>= 1) {
        if (wid >= step && wid < 2 * step && x < W_) {
            float* p = &red[wid - step][x][0];
            #pragma unroll
            for (int k = 0; k < 49; ++k) p[k] = acc[k];
        }
        __syncthreads();
        if (wid < step && x < W_) {
            const float* p = &red[wid][x][0];
            #pragma unroll
            for (int k = 0; k < 49; ++k) acc[k] += p[k];
        }
        __syncthreads();
    }

    // Wave 0: per-lane softmax over 49 taps + expected flow, all in registers.
    if (wid == 0 && x < W_) {
        float m = -1e30f;
        #pragma unroll
        for (int k = 0; k < 49; ++k) {
            const int dy = k / 7, dx = k % 7;
            const int row = y + dy - 3;
            const bool ok = (cmask[dx] != 0u) && (row >= 0) && (row < H_);
            const float c = ok ? acc[k] * 0.125f : -1e30f;
            acc[k] = c;                 // reuse acc as masked corr
            m = fmaxf(m, c);
        }
        float S = 0.0f, Sx = 0.0f, Sy = 0.0f;
        #pragma unroll
        for (int k = 0; k < 49; ++k) {
            const int dy = k / 7, dx = k % 7;
            const float e = (acc[k] > -1e29f) ? __expf(acc[k] - m) : 0.0f;
            S  += e;
            Sx += e * (float)(dx - 3);
            Sy += e * (float)(dy - 3);
        }
        const float inv = 1.0f / S;
        // out layout: (n, 2, s, h, w)
        const int ob = (n_idx * 2) * S_ * HW_ + s_idx * HW_ + y * W_ + x;
        out[ob]            = Sx * inv;
        out[ob + S_ * HW_] = Sy * inv;
    }
}

extern "C" void kernel_launch(void* const* d_in, const int* in_sizes, int n_in,
                              void* d_out, int out_size, void* d_ws, size_t ws_size,
                              hipStream_t stream) {
    const float* f0 = (const float*)d_in[0];
    const float* f1 = (const float*)d_in[1];
    float* out = (float*)d_out;

    flow_kernel<<<8 * H_, 512, 0, stream>>>(f0, f1, out);  // 512 blocks
}